// Round 1
// baseline (1123.384 us; speedup 1.0000x reference)
//
#include <hip/hip_runtime.h>
#include <stdint.h>

// Problem constants (from reference)
#define N_POINTS   34100
#define BATCH      8
#define N_GT       200
#define NLEV       5
#define NCAND      3500
#define MAX_DET    300
#define SCORE_TH   0.05f
#define NMS_TH     0.5f
#define IMG        1280.0f

// Output layout (float32 flat, reference return order)
#define OUT_MATCH  0        // 8*34100 = 272800
#define OUT_BOXES  272800   // 8*300*4 = 9600
#define OUT_SCORES 282400   // 8*300
#define OUT_LABELS 284800   // 8*300
#define OUT_VALID  287200   // 8*300  -> total 289600

// Workspace layout (bytes)
#define WS_KEYS    0                    // uint32[8*34100]  = 1,091,200 B
#define WS_CBOXES  1091200              // float[8*3500*4]  =   448,000 B (16B aligned)
#define WS_CSCORES 1539200              // float[8*3500]    =   112,000 B
// total 1,651,200 B

// ---------------------------------------------------------------------------
// Kernel 1: point->gt matching (argmin area among containing boxes, else -1)
//           + sigmoid sortable-key precompute for top-k.
// ---------------------------------------------------------------------------
__global__ __launch_bounds__(256)
void match_key_kernel(const float* __restrict__ points,
                      const float* __restrict__ gt,
                      const float* __restrict__ logits,
                      float* __restrict__ out_match,
                      uint32_t* __restrict__ keys) {
#pragma clang fp contract(off)
    __shared__ float bx1[N_GT], by1[N_GT], bx2[N_GT], by2[N_GT], ar[N_GT];
    const int b = blockIdx.y;
    const int p = blockIdx.x * blockDim.x + threadIdx.x;

    for (int j = threadIdx.x; j < N_GT; j += blockDim.x) {
        float x1 = gt[(b * N_GT + j) * 4 + 0];
        float y1 = gt[(b * N_GT + j) * 4 + 1];
        float x2 = gt[(b * N_GT + j) * 4 + 2];
        float y2 = gt[(b * N_GT + j) * 4 + 3];
        bx1[j] = x1; by1[j] = y1; bx2[j] = x2; by2[j] = y2;
        ar[j] = (x2 - x1) * (y2 - y1);
    }
    __syncthreads();
    if (p >= N_POINTS) return;

    const float px = points[p * 2 + 0];
    const float py = points[p * 2 + 1];
    const float BIGF = 2147483648.0f;   // float32(2^31 - 1) rounds to 2^31
    float best = BIGF;
    int bi = -1;
#pragma unroll 4
    for (int j = 0; j < N_GT; ++j) {
        bool inside = (px >= bx1[j]) && (px <= bx2[j]) &&
                      (py >= by1[j]) && (py <= by2[j]);
        float cost = inside ? ar[j] : BIGF;
        if (cost < best) { best = cost; bi = j; }   // strict < => first-occurrence argmin
    }
    out_match[b * N_POINTS + p] = (float)bi;

    // sigmoid -> monotone sortable uint32 key (scores in (0,1) => MSB-set branch)
    float lg = logits[b * N_POINTS + p];
    float s = 1.0f / (1.0f + expf(-lg));
    uint32_t u = __float_as_uint(s);
    uint32_t key = (u & 0x80000000u) ? ~u : (u | 0x80000000u);
    keys[b * N_POINTS + p] = key;
}

// ---------------------------------------------------------------------------
// Kernel 2: per-(batch,level) exact top-k via 48-bit radix select.
// Composite key = (score_key32 << 16) | (65535 - idx_in_level):
//   - unique per element -> kth key unique -> clean >= compaction
//   - ordering = (score desc, index asc) = lax.top_k tie semantics
// Then rank-by-counting among K selected, decode+clip boxes, write candidates.
// ---------------------------------------------------------------------------
__global__ __launch_bounds__(256)
void topk_decode_kernel(const uint32_t* __restrict__ keys,
                        const float* __restrict__ reg,
                        const float* __restrict__ points,
                        float* __restrict__ cboxes,
                        float* __restrict__ cscores) {
#pragma clang fp contract(off)
    const int lsize[NLEV] = {25600, 6400, 1600, 400, 100};
    const int loff[NLEV]  = {0, 25600, 32000, 33600, 34000};
    const int lk[NLEV]    = {1000, 1000, 1000, 400, 100};
    const int coff[NLEV]  = {0, 1000, 2000, 3000, 3400};

    const int l = blockIdx.x;     // level
    const int b = blockIdx.y;     // batch
    const int n = lsize[l];
    const int K = lk[l];
    const uint32_t* k32 = keys + b * N_POINTS + loff[l];

    __shared__ uint32_t hist[256];
    __shared__ unsigned long long selKeys[1000];
    __shared__ uint32_t s_chosen, s_kk, selCount;

    unsigned long long prefix = 0ull, pmask = 0ull;
    uint32_t kk = (uint32_t)K;

    for (int shift = 40; shift >= 0; shift -= 8) {
        for (int i = threadIdx.x; i < 256; i += blockDim.x) hist[i] = 0u;
        __syncthreads();
        for (int i = threadIdx.x; i < n; i += blockDim.x) {
            unsigned long long key =
                ((unsigned long long)k32[i] << 16) | (unsigned long long)(65535 - i);
            if ((key & pmask) == prefix)
                atomicAdd(&hist[(uint32_t)(key >> shift) & 255u], 1u);
        }
        __syncthreads();
        if (threadIdx.x == 0) {
            uint32_t c = 0;
            for (int bin = 255; bin >= 0; --bin) {
                uint32_t nc = c + hist[bin];
                if (nc >= kk) { s_chosen = (uint32_t)bin; s_kk = kk - c; break; }
                c = nc;
            }
        }
        __syncthreads();
        prefix |= ((unsigned long long)s_chosen) << shift;
        pmask  |= (0xFFull << shift);
        kk = s_kk;
        __syncthreads();
    }
    // prefix == K-th largest composite key (unique)

    if (threadIdx.x == 0) selCount = 0u;
    __syncthreads();
    for (int i = threadIdx.x; i < n; i += blockDim.x) {
        unsigned long long key =
            ((unsigned long long)k32[i] << 16) | (unsigned long long)(65535 - i);
        if (key >= prefix) {
            uint32_t pos = atomicAdd(&selCount, 1u);
            selKeys[pos] = key;              // exactly K elements (keys unique)
        }
    }
    __syncthreads();

    for (int i = threadIdx.x; i < K; i += blockDim.x) {
        unsigned long long ki = selKeys[i];
        int r = 0;
        for (int j = 0; j < K; ++j) r += (selKeys[j] > ki) ? 1 : 0;  // rank, desc

        uint32_t key32 = (uint32_t)(ki >> 16);
        int idxl = 65535 - (int)(ki & 0xFFFFull);
        uint32_t u = (key32 & 0x80000000u) ? (key32 ^ 0x80000000u) : ~key32;
        float score = __uint_as_float(u);

        int p  = loff[l] + idxl;
        int gp = b * N_POINTS + p;
        float l_ = reg[gp * 4 + 0] * IMG;
        float t_ = reg[gp * 4 + 1] * IMG;
        float r_ = reg[gp * 4 + 2] * IMG;
        float bb = reg[gp * 4 + 3] * IMG;
        float px = points[p * 2 + 0];
        float py = points[p * 2 + 1];
        float x1 = fminf(fmaxf(px - l_, 0.0f), IMG);
        float y1 = fminf(fmaxf(py - t_, 0.0f), IMG);
        float x2 = fminf(fmaxf(px + r_, 0.0f), IMG);
        float y2 = fminf(fmaxf(py + bb, 0.0f), IMG);

        int slot = b * NCAND + coff[l] + r;
        cboxes[slot * 4 + 0] = x1;
        cboxes[slot * 4 + 1] = y1;
        cboxes[slot * 4 + 2] = x2;
        cboxes[slot * 4 + 3] = y2;
        cscores[slot] = score;
    }
}

// ---------------------------------------------------------------------------
// Kernel 3: sequential NMS, one block per image. Boxes in LDS (SoA, 56 KB),
// work array in registers (7 per thread). Exact jnp.argmax tie semantics
// (first occurrence) via (val desc, idx asc) reduce.
// ---------------------------------------------------------------------------
#define NMS_T 512
__global__ __launch_bounds__(NMS_T)
void nms_kernel(const float* __restrict__ cboxes,
                const float* __restrict__ cscores,
                float* __restrict__ out) {
#pragma clang fp contract(off)
    __shared__ float sx1[NCAND], sy1[NCAND], sx2[NCAND], sy2[NCAND];
    __shared__ float pv[NMS_T / 64];
    __shared__ int   pi[NMS_T / 64];
    __shared__ float sBv;
    __shared__ int   sBi;

    const int b = blockIdx.x;
    const int tid = threadIdx.x;

    float w[7];
#pragma unroll
    for (int k = 0; k < 7; ++k) {
        int e = tid + k * NMS_T;
        if (e < NCAND) {
            const float4 bx = *(const float4*)(cboxes + (size_t)(b * NCAND + e) * 4);
            sx1[e] = bx.x; sy1[e] = bx.y; sx2[e] = bx.z; sy2[e] = bx.w;
            float s = cscores[b * NCAND + e];
            w[k] = (s > SCORE_TH) ? s : -INFINITY;
        } else {
            w[k] = -INFINITY;
        }
    }
    __syncthreads();

    float* ob = out + OUT_BOXES  + b * MAX_DET * 4;
    float* os = out + OUT_SCORES + b * MAX_DET;
    float* ol = out + OUT_LABELS + b * MAX_DET;
    float* ovp = out + OUT_VALID + b * MAX_DET;

    for (int it = 0; it < MAX_DET; ++it) {
        // local argmax (indices ascend with k => strict > keeps lowest index on tie)
        float bv = w[0];
        int   bi = tid;
#pragma unroll
        for (int k = 1; k < 7; ++k) {
            if (w[k] > bv) { bv = w[k]; bi = tid + k * NMS_T; }
        }
        // wave (64-lane) reduce: (val desc, idx asc)
#pragma unroll
        for (int off = 32; off >= 1; off >>= 1) {
            float ov = __shfl_down(bv, off);
            int   oi = __shfl_down(bi, off);
            if (ov > bv || (ov == bv && oi < bi)) { bv = ov; bi = oi; }
        }
        const int lane = tid & 63, wid = tid >> 6;
        if (lane == 0) { pv[wid] = bv; pi[wid] = bi; }
        __syncthreads();
        if (tid == 0) {
            for (int q = 1; q < NMS_T / 64; ++q) {
                if (pv[q] > bv || (pv[q] == bv && pi[q] < bi)) { bv = pv[q]; bi = pi[q]; }
            }
            sBv = bv; sBi = bi;
            bool valid = (bv != -INFINITY);
            os[it]  = valid ? bv : 0.0f;
            ol[it]  = valid ? 0.0f : -1.0f;
            ovp[it] = valid ? 1.0f : 0.0f;
            ob[it * 4 + 0] = valid ? sx1[bi] : 0.0f;
            ob[it * 4 + 1] = valid ? sy1[bi] : 0.0f;
            ob[it * 4 + 2] = valid ? sx2[bi] : 0.0f;
            ob[it * 4 + 3] = valid ? sy2[bi] : 0.0f;
        }
        __syncthreads();
        const float Bv = sBv;
        const int   Bi = sBi;
        if (Bv != -INFINITY) {   // if max is -inf, all are -inf: suppression is a no-op
            const float bx1 = sx1[Bi], by1 = sy1[Bi], bx2 = sx2[Bi], by2 = sy2[Bi];
            const float a1 = (bx2 - bx1) * (by2 - by1);
#pragma unroll
            for (int k = 0; k < 7; ++k) {
                int e = tid + k * NMS_T;
                if (e < NCAND && w[k] != -INFINITY) {
                    if (e == Bi) { w[k] = -INFINITY; continue; }
                    float ix1 = fmaxf(bx1, sx1[e]);
                    float iy1 = fmaxf(by1, sy1[e]);
                    float ix2 = fminf(bx2, sx2[e]);
                    float iy2 = fminf(by2, sy2[e]);
                    float inter = fmaxf(ix2 - ix1, 0.0f) * fmaxf(iy2 - iy1, 0.0f);
                    float a2 = (sx2[e] - sx1[e]) * (sy2[e] - sy1[e]);
                    float iou = inter / (a1 + a2 - inter + 1e-9f);
                    if (iou > NMS_TH) w[k] = -INFINITY;
                }
            }
        }
        // no barrier needed: suppression touches only private regs; LDS bests are
        // re-written only after the next iteration's barrier.
    }
}

// ---------------------------------------------------------------------------
extern "C" void kernel_launch(void* const* d_in, const int* in_sizes, int n_in,
                              void* d_out, int out_size, void* d_ws, size_t ws_size,
                              hipStream_t stream) {
    const float* points = (const float*)d_in[0];   // (34100, 2)
    const float* gt     = (const float*)d_in[1];   // (8, 200, 4)
    const float* logits = (const float*)d_in[2];   // (8, 34100, 1)
    const float* reg    = (const float*)d_in[3];   // (8, 34100, 4)
    float* out = (float*)d_out;

    uint32_t* keys  = (uint32_t*)((char*)d_ws + WS_KEYS);
    float* cboxes   = (float*)((char*)d_ws + WS_CBOXES);
    float* cscores  = (float*)((char*)d_ws + WS_CSCORES);

    dim3 g1((N_POINTS + 255) / 256, BATCH);
    match_key_kernel<<<g1, 256, 0, stream>>>(points, gt, logits, out + OUT_MATCH, keys);

    dim3 g2(NLEV, BATCH);
    topk_decode_kernel<<<g2, 256, 0, stream>>>(keys, reg, points, cboxes, cscores);

    nms_kernel<<<BATCH, NMS_T, 0, stream>>>(cboxes, cscores, out);
}

// Round 2
// 616.629 us; speedup vs baseline: 1.8218x; 1.8218x over previous
//
#include <hip/hip_runtime.h>
#include <stdint.h>

// Problem constants (from reference)
#define N_POINTS   34100
#define BATCH      8
#define N_GT       200
#define NLEV       5
#define NCAND      3500
#define MAX_DET    300
#define SCORE_TH   0.05f
#define NMS_TH     0.5f
#define IMG        1280.0f

// Output layout (float32 flat, reference return order)
#define OUT_MATCH  0        // 8*34100 = 272800
#define OUT_BOXES  272800   // 8*300*4 = 9600
#define OUT_SCORES 282400   // 8*300
#define OUT_LABELS 284800   // 8*300
#define OUT_VALID  287200   // 8*300  -> total 289600

// Workspace layout (bytes)
#define WS_KEYS    0           // uint32[8*34100]      = 1,091,200
#define WS_CKEYS   1091200     // uint64[8*3500]       =   224,000
#define WS_CBOXES  1315200     // float4[8*3500]       =   448,000
#define WS_CSCORES 1763200     // float [8*3500]       =   112,000
#define WS_SBOXES  1875200     // float4[8*3500]       =   448,000 (sorted)
#define WS_SSCORES 2323200     // float [8*3500]       =   112,000 (sorted)
#define WS_MASK    2435200     // uint64[8*98560]      = 6,307,840 (packed triangle)
// total ~8.75 MB
#define MASK_STRIDE 98560      // words per image (98540 used, padded)

// Packed upper-triangle row offset: row c stores words (c>>6)..54
__device__ __forceinline__ int mask_off(int c) {
    int g = c >> 6;
    return 64 * (55 * g - (g * (g - 1)) / 2) + (c - (g << 6)) * (55 - g);
}

// ---------------------------------------------------------------------------
// Kernel 1: point->gt matching + sigmoid sortable-key precompute. (unchanged)
// ---------------------------------------------------------------------------
__global__ __launch_bounds__(256)
void match_key_kernel(const float* __restrict__ points,
                      const float* __restrict__ gt,
                      const float* __restrict__ logits,
                      float* __restrict__ out_match,
                      uint32_t* __restrict__ keys) {
#pragma clang fp contract(off)
    __shared__ float bx1[N_GT], by1[N_GT], bx2[N_GT], by2[N_GT], ar[N_GT];
    const int b = blockIdx.y;
    const int p = blockIdx.x * blockDim.x + threadIdx.x;

    for (int j = threadIdx.x; j < N_GT; j += blockDim.x) {
        float x1 = gt[(b * N_GT + j) * 4 + 0];
        float y1 = gt[(b * N_GT + j) * 4 + 1];
        float x2 = gt[(b * N_GT + j) * 4 + 2];
        float y2 = gt[(b * N_GT + j) * 4 + 3];
        bx1[j] = x1; by1[j] = y1; bx2[j] = x2; by2[j] = y2;
        ar[j] = (x2 - x1) * (y2 - y1);
    }
    __syncthreads();
    if (p >= N_POINTS) return;

    const float px = points[p * 2 + 0];
    const float py = points[p * 2 + 1];
    const float BIGF = 2147483648.0f;
    float best = BIGF;
    int bi = -1;
#pragma unroll 4
    for (int j = 0; j < N_GT; ++j) {
        bool inside = (px >= bx1[j]) && (px <= bx2[j]) &&
                      (py >= by1[j]) && (py <= by2[j]);
        float cost = inside ? ar[j] : BIGF;
        if (cost < best) { best = cost; bi = j; }
    }
    out_match[b * N_POINTS + p] = (float)bi;

    float lg = logits[b * N_POINTS + p];
    float s = 1.0f / (1.0f + expf(-lg));
    uint32_t u = __float_as_uint(s);
    uint32_t key = (u & 0x80000000u) ? ~u : (u | 0x80000000u);
    keys[b * N_POINTS + p] = key;
}

// ---------------------------------------------------------------------------
// Kernel 2: per-(batch,level) exact top-k via 48-bit radix select + O(K^2)
// rank. Bin scan now wave-parallel (was the thread-0 LDS latency chain).
// Additionally emits the 50-bit global-order key64 for the merge sort.
// ---------------------------------------------------------------------------
__global__ __launch_bounds__(256)
void topk_decode_kernel(const uint32_t* __restrict__ keys,
                        const float* __restrict__ reg,
                        const float* __restrict__ points,
                        float* __restrict__ cboxes,
                        float* __restrict__ cscores,
                        unsigned long long* __restrict__ ckeys) {
#pragma clang fp contract(off)
    const int lsize[NLEV] = {25600, 6400, 1600, 400, 100};
    const int loff[NLEV]  = {0, 25600, 32000, 33600, 34000};
    const int lk[NLEV]    = {1000, 1000, 1000, 400, 100};
    const int coff[NLEV]  = {0, 1000, 2000, 3000, 3400};

    const int l = blockIdx.x;
    const int b = blockIdx.y;
    const int n = lsize[l];
    const int K = lk[l];
    const uint32_t* k32 = keys + b * N_POINTS + loff[l];
    const int tid = threadIdx.x;

    __shared__ uint32_t hist[256];
    __shared__ unsigned long long selKeys[1000];
    __shared__ uint32_t s_chosen, s_kk, selCount;

    if (tid == 0) s_kk = (uint32_t)K;
    unsigned long long prefix = 0ull, pmask = 0ull;

    for (int shift = 40; shift >= 0; shift -= 8) {
        for (int i = tid; i < 256; i += blockDim.x) hist[i] = 0u;
        __syncthreads();
        for (int i = tid; i < n; i += blockDim.x) {
            unsigned long long key =
                ((unsigned long long)k32[i] << 16) | (unsigned long long)(65535 - i);
            if ((key & pmask) == prefix)
                atomicAdd(&hist[(uint32_t)(key >> shift) & 255u], 1u);
        }
        __syncthreads();
        if (tid < 64) {
            // lane L owns bins 4L..4L+3; suffix-sum from bin 255 downward
            uint32_t h0 = hist[4 * tid], h1 = hist[4 * tid + 1];
            uint32_t h2 = hist[4 * tid + 2], h3 = hist[4 * tid + 3];
            uint32_t G = h0 + h1 + h2 + h3;
            uint32_t acc = G;
#pragma unroll
            for (int off = 1; off < 64; off <<= 1) {
                uint32_t v = (uint32_t)__shfl_down((int)acc, off);
                if (tid + off < 64) acc += v;
            }
            uint32_t kkv = s_kk;
            uint32_t se3 = acc - G;        // sum over bins > 4t+3
            uint32_t se2 = se3 + h3, se1 = se2 + h2, se0 = se1 + h1;
            if (se3 < kkv && se3 + h3 >= kkv) { s_chosen = 4 * tid + 3; s_kk = kkv - se3; }
            if (se2 < kkv && se2 + h2 >= kkv) { s_chosen = 4 * tid + 2; s_kk = kkv - se2; }
            if (se1 < kkv && se1 + h1 >= kkv) { s_chosen = 4 * tid + 1; s_kk = kkv - se1; }
            if (se0 < kkv && se0 + h0 >= kkv) { s_chosen = 4 * tid;     s_kk = kkv - se0; }
        }
        __syncthreads();
        prefix |= ((unsigned long long)s_chosen) << shift;
        pmask  |= (0xFFull << shift);
        __syncthreads();
    }
    // prefix == K-th largest composite key (unique)

    if (tid == 0) selCount = 0u;
    __syncthreads();
    for (int i = tid; i < n; i += blockDim.x) {
        unsigned long long key =
            ((unsigned long long)k32[i] << 16) | (unsigned long long)(65535 - i);
        if (key >= prefix) {
            uint32_t pos = atomicAdd(&selCount, 1u);
            selKeys[pos] = key;
        }
    }
    __syncthreads();

    for (int i = tid; i < K; i += blockDim.x) {
        unsigned long long ki = selKeys[i];
        int r = 0;
#pragma unroll 8
        for (int j = 0; j < K; ++j) r += (selKeys[j] > ki) ? 1 : 0;

        uint32_t key32 = (uint32_t)(ki >> 16);
        int idxl = 65535 - (int)(ki & 0xFFFFull);
        uint32_t u = (key32 & 0x80000000u) ? (key32 ^ 0x80000000u) : ~key32;
        float score = __uint_as_float(u);

        int p  = loff[l] + idxl;
        int gp = b * N_POINTS + p;
        float l_ = reg[gp * 4 + 0] * IMG;
        float t_ = reg[gp * 4 + 1] * IMG;
        float r_ = reg[gp * 4 + 2] * IMG;
        float bb = reg[gp * 4 + 3] * IMG;
        float px = points[p * 2 + 0];
        float py = points[p * 2 + 1];
        float x1 = fminf(fmaxf(px - l_, 0.0f), IMG);
        float y1 = fminf(fmaxf(py - t_, 0.0f), IMG);
        float x2 = fminf(fmaxf(px + r_, 0.0f), IMG);
        float y2 = fminf(fmaxf(py + bb, 0.0f), IMG);

        int slot = b * NCAND + coff[l] + r;
        cboxes[slot * 4 + 0] = x1;
        cboxes[slot * 4 + 1] = y1;
        cboxes[slot * 4 + 2] = x2;
        cboxes[slot * 4 + 3] = y2;
        cscores[slot] = score;
        // 50-bit global-order key: (score desc, level asc, idx-in-level asc)
        ckeys[slot] = ((unsigned long long)key32 << 18)
                    | ((unsigned long long)(7 - l) << 15)
                    | (unsigned long long)(32767 - idxl);
    }
}

// ---------------------------------------------------------------------------
// Kernel 3: merge-rank the 5 sorted level runs into a global sorted order.
// Rank = pos-in-own-run + sum of binary-search counts in the other 4 runs.
// ---------------------------------------------------------------------------
__global__ __launch_bounds__(512)
void sort_kernel(const unsigned long long* __restrict__ ckeys,
                 const float* __restrict__ cboxes,
                 const float* __restrict__ cscores,
                 float* __restrict__ sboxes,
                 float* __restrict__ sscores) {
    __shared__ unsigned long long sk[NCAND];
    const int b = blockIdx.x;
    const int tid = threadIdx.x;
    const unsigned long long* gk = ckeys + b * NCAND;
    for (int i = tid; i < NCAND; i += 512) sk[i] = gk[i];
    __syncthreads();

    const int loff_[NLEV] = {0, 1000, 2000, 3000, 3400};
    const int lk_[NLEV]   = {1000, 1000, 1000, 400, 100};

    for (int s = tid; s < NCAND; s += 512) {
        unsigned long long mk = sk[s];
        int l = (s < 1000) ? 0 : (s < 2000) ? 1 : (s < 3000) ? 2 : (s < 3400) ? 3 : 4;
        int r = s - loff_[l];
#pragma unroll
        for (int q = 0; q < NLEV; ++q) {
            if (q == l) continue;
            const unsigned long long* a = sk + loff_[q];
            int lo = 0, hi = lk_[q];
            while (lo < hi) {          // count of keys > mk in desc-sorted run
                int mid = (lo + hi) >> 1;
                if (a[mid] > mk) lo = mid + 1; else hi = mid;
            }
            r += lo;
        }
        float4 bx = ((const float4*)cboxes)[b * NCAND + s];
        ((float4*)sboxes)[b * NCAND + r] = bx;
        sscores[b * NCAND + r] = cscores[b * NCAND + s];
    }
}

// ---------------------------------------------------------------------------
// Kernel 4: suppression-mask matrix, packed upper triangle, 64 IoUs/ballot.
// Row c word w (w in [c>>6, 54]): bit j of word = (IoU(c, 64w+j) > 0.5).
// Rows for below-threshold c skipped (never kept, never read).
// ---------------------------------------------------------------------------
__global__ __launch_bounds__(256)
void mask_kernel(const float* __restrict__ sboxes,
                 const float* __restrict__ sscores,
                 unsigned long long* __restrict__ mask) {
#pragma clang fp contract(off)
    __shared__ float4 sb[3520];
    const int b = blockIdx.y;
    const int tid = threadIdx.x;
    const float4* gb = (const float4*)sboxes + b * NCAND;
    for (int i = tid; i < 3520; i += 256)
        sb[i] = (i < NCAND) ? gb[i] : make_float4(0.f, 0.f, 0.f, 0.f);
    __syncthreads();

    const int lane = tid & 63;
    const int wv = tid >> 6;
    unsigned long long* mrow = mask + (size_t)b * MASK_STRIDE;
    const float* ssc = sscores + b * NCAND;
    const int stride = gridDim.x * 4;

    for (int c = blockIdx.x * 4 + wv; c < NCAND; c += stride) {
        if (!(ssc[c] > SCORE_TH)) continue;          // wave-uniform
        float4 bc = sb[c];
        float a1 = (bc.z - bc.x) * (bc.w - bc.y);
        int g = c >> 6;
        int off = mask_off(c);
        for (int w = g; w < 55; ++w) {
            float4 bj = sb[(w << 6) + lane];
            float x1 = fmaxf(bc.x, bj.x);
            float y1 = fmaxf(bc.y, bj.y);
            float x2 = fminf(bc.z, bj.z);
            float y2 = fminf(bc.w, bj.w);
            float inter = fmaxf(x2 - x1, 0.f) * fmaxf(y2 - y1, 0.f);
            float a2 = (bj.z - bj.x) * (bj.w - bj.y);
            float iou = inter / (a1 + a2 - inter + 1e-9f);  // IEEE div = reference
            unsigned long long bits = __ballot(iou > NMS_TH);
            if (lane == 0) mrow[off + (w - g)] = bits;
        }
    }
}

// ---------------------------------------------------------------------------
// Kernel 5: sorted-order NMS scan. One wave per image; suppressed bitmask in
// lane registers (lane L owns word L). ctz jumps to next live candidate; on
// keep, current word's bits recomputed in-wave (LDS boxes), future words ORed
// from precomputed rows (latency off the decision chain).
// ---------------------------------------------------------------------------
__global__ __launch_bounds__(256)
void scan_kernel(const float* __restrict__ sboxes,
                 const float* __restrict__ sscores,
                 const unsigned long long* __restrict__ mask,
                 float* __restrict__ out) {
#pragma clang fp contract(off)
    __shared__ float4 sb[3520];
    const int b = blockIdx.x;
    const int tid = threadIdx.x;
    const float4* gb = (const float4*)sboxes + b * NCAND;
    for (int i = tid; i < 3520; i += 256)
        sb[i] = (i < NCAND) ? gb[i] : make_float4(0.f, 0.f, 0.f, 0.f);
    __syncthreads();
    if (tid >= 64) return;

    const int lane = tid;
    const float* ssc = sscores + b * NCAND;
    const unsigned long long* mrow = mask + (size_t)b * MASK_STRIDE;

    // init: pre-suppress below-threshold and out-of-range candidates
    unsigned long long m = 0ull;
    for (int w = 0; w < 55; ++w) {
        int c = (w << 6) + lane;
        bool ok = (c < NCAND) && (ssc[c] > SCORE_TH);
        unsigned long long bal = __ballot(!ok);
        if (lane == w) m |= bal;
    }

    float* ob = out + OUT_BOXES  + b * MAX_DET * 4;
    float* os = out + OUT_SCORES + b * MAX_DET;
    float* ol = out + OUT_LABELS + b * MAX_DET;
    float* ov = out + OUT_VALID  + b * MAX_DET;

    int kept = 0;
    for (int w = 0; w < 55 && kept < MAX_DET; ++w) {
        unsigned long long cur = __shfl(m, w);
        while (kept < MAX_DET) {
            unsigned long long avail = ~cur;
            if (avail == 0ull) break;
            int t = __builtin_ctzll(avail);
            int c = (w << 6) + t;
            float s = ssc[c];                 // issue early, used only for output
            float4 bc = sb[c];
            // OR this row's future words into lane-owned mask (off the chain)
            int off = mask_off(c);
            if (lane >= w && lane < 55) m |= mrow[off + (lane - w)];
            // recompute current word's suppression bits in-wave (fast path)
            float4 bj = sb[(w << 6) + lane];
            float a1 = (bc.z - bc.x) * (bc.w - bc.y);
            float x1 = fmaxf(bc.x, bj.x);
            float y1 = fmaxf(bc.y, bj.y);
            float x2 = fminf(bc.z, bj.z);
            float y2 = fminf(bc.w, bj.w);
            float inter = fmaxf(x2 - x1, 0.f) * fmaxf(y2 - y1, 0.f);
            float a2 = (bj.z - bj.x) * (bj.w - bj.y);
            float iou = inter / (a1 + a2 - inter + 1e-9f);
            cur |= __ballot(iou > NMS_TH) | (1ull << t);
            if (lane == 0) {
                ob[kept * 4 + 0] = bc.x;
                ob[kept * 4 + 1] = bc.y;
                ob[kept * 4 + 2] = bc.z;
                ob[kept * 4 + 3] = bc.w;
                os[kept] = s;
                ol[kept] = 0.0f;
                ov[kept] = 1.0f;
            }
            kept++;
        }
    }
    // fill remaining slots (reference: argmax over all -inf -> invalid picks)
    for (int k = kept + lane; k < MAX_DET; k += 64) {
        ob[k * 4 + 0] = 0.f; ob[k * 4 + 1] = 0.f;
        ob[k * 4 + 2] = 0.f; ob[k * 4 + 3] = 0.f;
        os[k] = 0.f; ol[k] = -1.f; ov[k] = 0.f;
    }
}

// ---------------------------------------------------------------------------
extern "C" void kernel_launch(void* const* d_in, const int* in_sizes, int n_in,
                              void* d_out, int out_size, void* d_ws, size_t ws_size,
                              hipStream_t stream) {
    const float* points = (const float*)d_in[0];   // (34100, 2)
    const float* gt     = (const float*)d_in[1];   // (8, 200, 4)
    const float* logits = (const float*)d_in[2];   // (8, 34100, 1)
    const float* reg    = (const float*)d_in[3];   // (8, 34100, 4)
    float* out = (float*)d_out;

    uint32_t* keys = (uint32_t*)((char*)d_ws + WS_KEYS);
    unsigned long long* ckeys = (unsigned long long*)((char*)d_ws + WS_CKEYS);
    float* cboxes  = (float*)((char*)d_ws + WS_CBOXES);
    float* cscores = (float*)((char*)d_ws + WS_CSCORES);
    float* sboxes  = (float*)((char*)d_ws + WS_SBOXES);
    float* sscores = (float*)((char*)d_ws + WS_SSCORES);
    unsigned long long* mask = (unsigned long long*)((char*)d_ws + WS_MASK);

    dim3 g1((N_POINTS + 255) / 256, BATCH);
    match_key_kernel<<<g1, 256, 0, stream>>>(points, gt, logits, out + OUT_MATCH, keys);

    dim3 g2(NLEV, BATCH);
    topk_decode_kernel<<<g2, 256, 0, stream>>>(keys, reg, points, cboxes, cscores, ckeys);

    sort_kernel<<<BATCH, 512, 0, stream>>>(ckeys, cboxes, cscores, sboxes, sscores);

    dim3 g4(32, BATCH);
    mask_kernel<<<g4, 256, 0, stream>>>(sboxes, sscores, mask);

    scan_kernel<<<BATCH, 256, 0, stream>>>(sboxes, sscores, mask, out);
}